// Round 1
// baseline (372.156 us; speedup 1.0000x reference)
//
#include <hip/hip_runtime.h>

// MaxMin pooling: in [C=..., H], windows of 4 along H.
// out[c, 2i]   = argmax(window) as float (first-occurrence ties)
// out[c, 2i+1] = min(window)
// One thread per window: float4 load (16B/lane), float2 store (8B/lane).
// Memory-bound: 256 MiB read + 128 MiB write -> ~64 us floor at 6.3 TB/s.

__global__ __launch_bounds__(256) void maxmin_kernel(
    const float4* __restrict__ in, float2* __restrict__ out, int nwin_total)
{
    int i = blockIdx.x * blockDim.x + threadIdx.x;
    if (i >= nwin_total) return;

    float4 w = in[i];

    // argmax with first-occurrence tie semantics (strict >)
    float m   = w.x;
    float idx = 0.0f;
    if (w.y > m) { m = w.y; idx = 1.0f; }
    if (w.z > m) { m = w.z; idx = 2.0f; }
    if (w.w > m) { m = w.w; idx = 3.0f; }

    float mn = fminf(fminf(w.x, w.y), fminf(w.z, w.w));

    out[i] = make_float2(idx, mn);
}

extern "C" void kernel_launch(void* const* d_in, const int* in_sizes, int n_in,
                              void* d_out, int out_size, void* d_ws, size_t ws_size,
                              hipStream_t stream)
{
    const float* in = (const float*)d_in[0];
    float* out = (float*)d_out;

    int nwin_total = in_sizes[0] / 4;   // 4096*16384/4 = 16,777,216 windows
    int block = 256;
    int grid = (nwin_total + block - 1) / block;

    maxmin_kernel<<<grid, block, 0, stream>>>(
        (const float4*)in, (float2*)out, nwin_total);
}